// Round 11
// baseline (861.152 us; speedup 1.0000x reference)
//
#include <hip/hip_runtime.h>

#define HDIM 256

typedef __attribute__((ext_vector_type(8))) short short8;
typedef __attribute__((ext_vector_type(4))) float f32x4;

typedef const __attribute__((address_space(1))) unsigned int* gas_ptr;
typedef __attribute__((address_space(3))) unsigned int* las_ptr;

__device__ __forceinline__ unsigned short f2bf(float f) {
    unsigned int u = __float_as_uint(f);
    u += 0x7FFF + ((u >> 16) & 1);   // round-to-nearest-even
    return (unsigned short)(u >> 16);
}
__device__ __forceinline__ float bf2f(unsigned short u) {
    return __uint_as_float(((unsigned int)u) << 16);
}

__device__ __forceinline__ void acc_edge(float (&acc)[8], const float (&c)[8], short8 u) {
    #pragma unroll
    for (int k = 0; k < 8; k++)
        acc[k] += fmaxf(bf2f((unsigned short)u[k]) + c[k], 0.f);
}

// ---------------- CSR build ----------------

__global__ void k_zero_int(int* p, int n) {
    int i = blockIdx.x * blockDim.x + threadIdx.x;
    if (i < n) p[i] = 0;
}

__global__ void k_hist(const int* __restrict__ src, const int* __restrict__ dst,
                       int E, int* __restrict__ deg) {
    int e = blockIdx.x * blockDim.x + threadIdx.x;
    if (e >= E) return;
    atomicAdd(&deg[dst[e]], 1);
    atomicAdd(&deg[src[e]], 1);
}

__global__ void k_scan_partial(const int* __restrict__ deg, int* __restrict__ rp,
                               int* __restrict__ bsum, int n) {
    __shared__ int sd[256];
    int t = threadIdx.x;
    int base = blockIdx.x * 1024 + t * 4;
    int v[4]; int tsum = 0;
    #pragma unroll
    for (int k = 0; k < 4; k++) { v[k] = (base + k < n) ? deg[base + k] : 0; tsum += v[k]; }
    sd[t] = tsum; __syncthreads();
    for (int off = 1; off < 256; off <<= 1) {
        int x = (t >= off) ? sd[t - off] : 0;
        __syncthreads();
        sd[t] += x;
        __syncthreads();
    }
    int run = sd[t] - tsum;
    if (t == 255) bsum[blockIdx.x] = sd[255];
    #pragma unroll
    for (int k = 0; k < 4; k++) { if (base + k < n) rp[base + k] = run; run += v[k]; }
}

__global__ void k_scan_bsum(int* __restrict__ bsum, int nb) {
    __shared__ int sd[256];
    int t = threadIdx.x;
    int base = t * 4;
    int v[4]; int tsum = 0;
    #pragma unroll
    for (int k = 0; k < 4; k++) { v[k] = (base + k < nb) ? bsum[base + k] : 0; tsum += v[k]; }
    sd[t] = tsum; __syncthreads();
    for (int off = 1; off < 256; off <<= 1) {
        int x = (t >= off) ? sd[t - off] : 0;
        __syncthreads();
        sd[t] += x;
        __syncthreads();
    }
    int run = sd[t] - tsum;
    #pragma unroll
    for (int k = 0; k < 4; k++) { if (base + k < nb) bsum[base + k] = run; run += v[k]; }
}

__global__ void k_scan_add(int* __restrict__ rp, int* __restrict__ cursor,
                           const int* __restrict__ bsum, int n, int twoE) {
    int i = blockIdx.x * blockDim.x + threadIdx.x;
    if (i < n) {
        int v = rp[i] + bsum[i >> 10];
        rp[i] = v;
        cursor[i] = v;
    }
    if (i == 0) rp[n] = twoE;
}

__global__ void k_fill(const int* __restrict__ src, const int* __restrict__ dst,
                       int E, int* __restrict__ cursor, int* __restrict__ col) {
    int e = blockIdx.x * blockDim.x + threadIdx.x;
    if (e >= E) return;
    int s = src[e], d = dst[e];
    int p = atomicAdd(&cursor[d], 1); col[p] = s;
    int q = atomicAdd(&cursor[s], 1); col[q] = d;
}

// ---------------- weight prep ----------------

__global__ void k_prep_w(const float* __restrict__ W, unsigned short* __restrict__ Wt) {
    int k = blockIdx.x, nn = threadIdx.x;
    Wt[nn * 256 + k] = f2bf(W[k * 256 + nn]);
}

__global__ void k_prep_w0(const float* __restrict__ W0, unsigned short* __restrict__ Wt0) {
    int k = blockIdx.x, nn = threadIdx.x;
    Wt0[nn * 96 + k] = (k < 88) ? f2bf(W0[k * 256 + nn]) : 0;
}

// ---------------- embed + GEMM0 (88 -> 256), MFMA, bf16 out ----------------

__global__ __launch_bounds__(256) void k_embed0(
    const int* __restrict__ atom,
    const float* __restrict__ eE, const float* __restrict__ eD,
    const float* __restrict__ eV, const float* __restrict__ eC,
    const float* __restrict__ eA, const float* __restrict__ eH,
    const float* __restrict__ eHy,
    const unsigned short* __restrict__ Wt0, const float* __restrict__ b0,
    unsigned short* __restrict__ x, int n) {
    __shared__ __align__(128) unsigned short As[64 * 256];  // 32 KB
    int t = threadIdx.x;
    size_t node0 = (size_t)blockIdx.x * 64;

    {
        int row = t >> 2;
        int ks  = (t & 3) * 24;
        size_t node = node0 + row;
        int a0 = 0, a1 = 0, a2 = 0, a3 = 0, a4 = 0, a5 = 0, a6 = 0;
        bool ok = node < (size_t)n;
        if (ok) {
            const int* a = atom + node * 7;
            a0 = a[0]; a1 = a[1]; a2 = a[2]; a3 = a[3]; a4 = a[4]; a5 = a[5]; a6 = a[6];
        }
        #pragma unroll
        for (int kk = 0; kk < 24; kk++) {
            int k = ks + kk;
            float val = 0.f;
            if (ok) {
                if (k < 64)       val = eE[a0 * 64 + k];
                else if (k < 68)  val = eD[a1 * 4 + (k - 64)];
                else if (k < 72)  val = eV[(a2 + 1) * 4 + (k - 68)];
                else if (k < 76)  val = eC[a3 * 4 + (k - 72)];
                else if (k < 80)  val = eA[a4 * 4 + (k - 76)];
                else if (k < 84)  val = eH[a5 * 4 + (k - 80)];
                else if (k < 88)  val = eHy[a6 * 4 + (k - 84)];
            }
            int boff = (k * 2) ^ ((row & 7) << 4);
            *(unsigned short*)((char*)As + row * 256 + boff) = f2bf(val);
        }
    }
    __syncthreads();

    int w  = t >> 6;
    int l  = t & 63;
    int lr = l & 15;
    int lk = l >> 4;

    f32x4 acc[4][4];
    #pragma unroll
    for (int rg = 0; rg < 4; rg++)
        #pragma unroll
        for (int cg = 0; cg < 4; cg++)
            acc[rg][cg] = (f32x4){0.f, 0.f, 0.f, 0.f};

    #pragma unroll
    for (int kt = 0; kt < 3; kt++) {
        int kbyte = kt * 64 + lk * 16;
        short8 a[4], bf[4];
        #pragma unroll
        for (int rg = 0; rg < 4; rg++) {
            int row = rg * 16 + lr;
            a[rg] = *(const short8*)((const char*)As + row * 256 + (kbyte ^ ((row & 7) << 4)));
        }
        #pragma unroll
        for (int cg = 0; cg < 4; cg++) {
            int coln = w * 64 + cg * 16 + lr;
            bf[cg] = *(const short8*)((const char*)Wt0 + coln * 192 + kbyte);
        }
        #pragma unroll
        for (int rg = 0; rg < 4; rg++)
            #pragma unroll
            for (int cg = 0; cg < 4; cg++)
                acc[rg][cg] = __builtin_amdgcn_mfma_f32_16x16x32_bf16(a[rg], bf[cg], acc[rg][cg], 0, 0, 0);
    }

    float bcol[4];
    #pragma unroll
    for (int cg = 0; cg < 4; cg++) bcol[cg] = b0[w * 64 + cg * 16 + lr];

    __syncthreads();   // As reads done; reuse for bf16 repack (512B/row swizzled)
    #pragma unroll
    for (int rg = 0; rg < 4; rg++)
        #pragma unroll
        for (int j = 0; j < 4; j++) {
            int row = rg * 16 + lk * 4 + j;
            #pragma unroll
            for (int cg = 0; cg < 4; cg++) {
                int colI = w * 64 + cg * 16 + lr;
                int byte = row * 512 + ((((colI >> 2) << 3) ^ ((row & 7) << 4)) + (colI & 3) * 2);
                *(unsigned short*)((char*)As + byte) = f2bf(acc[rg][cg][j] + bcol[cg]);
            }
        }
    __syncthreads();
    ushort4* xo = (ushort4*)(x + node0 * HDIM);
    #pragma unroll
    for (int i = 0; i < 16; i++) {
        int g4 = i * 256 + t;
        int row = g4 >> 6, c4 = g4 & 63;
        if (node0 + row < (size_t)n)
            xo[g4] = *(ushort4*)((char*)As + row * 512 + ((c4 << 3) ^ ((row & 7) << 4)));
    }
}

// ---------------- fused GINE layer: gather -> LDS -> MFMA -> LN -> bf16 out ----------------
// 512 threads, 64 nodes/block. Phase 1: half-wave hh = wid*2+h statically owns rows
// hh*4..hh*4+3; their CSR ranges are CONTIGUOUS -> one 32-lane col-window load covers
// all 4 nodes. Two node-streams gathered interleaved (4 row loads in flight). All loop
// bounds half-uniform; every __shfl sources its own (fully active) half.
// Phase 2: swapped-operand MFMA (A=Wt[feature][k], B=node rows). Epilogue: LN + direct
// 8B global stores (lane holds 4 consecutive features of one node).

__global__ __launch_bounds__(512) void k_gine(
    const unsigned short* __restrict__ x, const int* __restrict__ rp,
    const int* __restrict__ col, const float* __restrict__ We,
    const float* __restrict__ be, const unsigned short* __restrict__ Wt,
    const float* __restrict__ b, const float* __restrict__ g,
    const float* __restrict__ bt, unsigned short* __restrict__ xout, int n) {
    __shared__ __align__(128) unsigned short As[64 * 256];   // 32 KB, 512B/row swizzled
    __shared__ float psum[8][64], psq[8][64];
    __shared__ float mean_s[64], inv_s[64];

    int t = threadIdx.x;
    int wid = t >> 6;       // 0..7
    int l = t & 63;
    int h = l >> 5;
    int j = l & 31;
    size_t node0 = (size_t)blockIdx.x * 64;

    // ---- phase 1: windowed gather + relu + sum, write rows to LDS ----
    {
        int hh = wid * 2 + h;                  // 0..15
        int row0 = hh * 4;
        const short8* x8 = (const short8*)x;   // 32 chunks of 16B per row
        float c[8];
        {
            float4 w0 = ((const float4*)We)[2 * j], w1 = ((const float4*)We)[2 * j + 1];
            float4 e0 = ((const float4*)be)[2 * j], e1 = ((const float4*)be)[2 * j + 1];
            c[0] = w0.x + e0.x; c[1] = w0.y + e0.y; c[2] = w0.z + e0.z; c[3] = w0.w + e0.w;
            c[4] = w1.x + e1.x; c[5] = w1.y + e1.y; c[6] = w1.z + e1.z; c[7] = w1.w + e1.w;
        }

        int off = h << 5;
        int base = (int)node0 + row0;

        // rp window [base, base+4] (clamped), one lane-parallel load + broadcast
        int rpv = 0;
        if (j < 5) {
            int bi = base + j;
            if (bi > n) bi = n;
            rpv = rp[bi];
        }
        int p0 = __shfl(rpv, off + 0, 64);
        int p1 = __shfl(rpv, off + 1, 64);
        int p2 = __shfl(rpv, off + 2, 64);
        int p3 = __shfl(rpv, off + 3, 64);
        int p4 = __shfl(rpv, off + 4, 64);

        // col window: one coalesced load covers all 4 nodes (if total <= 32)
        int total = p4 - p0;
        int idxr = (j < total) ? col[p0 + j] : 0;

        // ---- pass A: rows row0, row0+1 ----
        #pragma unroll
        for (int pass = 0; pass < 2; pass++) {
            int rA = row0 + pass * 2;
            int qa = (pass == 0) ? p0 : p2;
            int qb = (pass == 0) ? p1 : p3;
            int qc = (pass == 0) ? p2 : p4;
            int d0 = qb - qa, d1 = qc - qb;
            int oa = qa - p0, ob = qb - p0;

            float acc0[8], acc1[8];
            {
                size_t nA = node0 + rA, nB = node0 + rA + 1;
                bool ok0 = nA < (size_t)n, ok1 = nB < (size_t)n;
                short8 s0 = x8[(ok0 ? nA : 0) * 32 + j];
                short8 s1 = x8[(ok1 ? nB : 0) * 32 + j];
                #pragma unroll
                for (int k = 0; k < 8; k++) {
                    acc0[k] = ok0 ? bf2f((unsigned short)s0[k]) : 0.f;
                    acc1[k] = ok1 ? bf2f((unsigned short)s1[k]) : 0.f;
                }
            }

            if (qc - p0 <= 32) {
                // fast: both streams' indices live in idxr
                int e0 = 0, e1 = 0;
                int n2 = (d0 < d1) ? d0 : d1;
                for (; e0 + 2 <= n2; e0 += 2, e1 += 2) {
                    int i0 = __shfl(idxr, off + oa + e0, 64);
                    int i1 = __shfl(idxr, off + oa + e0 + 1, 64);
                    int i2 = __shfl(idxr, off + ob + e1, 64);
                    int i3 = __shfl(idxr, off + ob + e1 + 1, 64);
                    short8 u0 = x8[(size_t)i0 * 32 + j];
                    short8 u1 = x8[(size_t)i1 * 32 + j];
                    short8 u2 = x8[(size_t)i2 * 32 + j];
                    short8 u3 = x8[(size_t)i3 * 32 + j];
                    acc_edge(acc0, c, u0); acc_edge(acc0, c, u1);
                    acc_edge(acc1, c, u2); acc_edge(acc1, c, u3);
                }
                if (e0 < n2) {
                    int i0 = __shfl(idxr, off + oa + e0, 64);
                    int i2 = __shfl(idxr, off + ob + e1, 64);
                    short8 u0 = x8[(size_t)i0 * 32 + j];
                    short8 u2 = x8[(size_t)i2 * 32 + j];
                    acc_edge(acc0, c, u0); acc_edge(acc1, c, u2);
                    e0++; e1++;
                }
                for (; e0 < d0; e0++) {
                    int i0 = __shfl(idxr, off + oa + e0, 64);
                    short8 u0 = x8[(size_t)i0 * 32 + j];
                    acc_edge(acc0, c, u0);
                }
                for (; e1 < d1; e1++) {
                    int i2 = __shfl(idxr, off + ob + e1, 64);
                    short8 u2 = x8[(size_t)i2 * 32 + j];
                    acc_edge(acc1, c, u2);
                }
            } else {
                // slow (rare): uniform-address col loads, no shfl
                for (int e = 0; e < d0; e++) {
                    int s = col[qa + e];
                    short8 u = x8[(size_t)s * 32 + j];
                    acc_edge(acc0, c, u);
                }
                for (int e = 0; e < d1; e++) {
                    int s = col[qb + e];
                    short8 u = x8[(size_t)s * 32 + j];
                    acc_edge(acc1, c, u);
                }
            }

            short8 o0, o1;
            #pragma unroll
            for (int k = 0; k < 8; k++) {
                o0[k] = (short)f2bf(acc0[k]);
                o1[k] = (short)f2bf(acc1[k]);
            }
            int r1 = rA + 1;
            *(short8*)((char*)As + rA * 512 + ((j ^ (rA & 7)) << 4)) = o0;
            *(short8*)((char*)As + r1 * 512 + ((j ^ (r1 & 7)) << 4)) = o1;
        }
    }
    __syncthreads();

    // ---- phase 2: MFMA (A = Wt features, B = node rows) ----
    int lr = l & 15;
    int lk = l >> 4;

    f32x4 acc[2][4];        // [fg][ng]
    #pragma unroll
    for (int fg = 0; fg < 2; fg++)
        #pragma unroll
        for (int ng = 0; ng < 4; ng++)
            acc[fg][ng] = (f32x4){0.f, 0.f, 0.f, 0.f};

    #pragma unroll
    for (int kt = 0; kt < 8; kt++) {
        int kbyte = kt * 64 + lk * 16;
        short8 a[2], bfr[4];
        #pragma unroll
        for (int fg = 0; fg < 2; fg++) {
            int feat = wid * 32 + fg * 16 + lr;
            a[fg] = *(const short8*)((const char*)Wt + feat * 512 + kbyte);
        }
        #pragma unroll
        for (int ng = 0; ng < 4; ng++) {
            int row = ng * 16 + lr;
            bfr[ng] = *(const short8*)((const char*)As + row * 512 + (kbyte ^ ((row & 7) << 4)));
        }
        #pragma unroll
        for (int fg = 0; fg < 2; fg++)
            #pragma unroll
            for (int ng = 0; ng < 4; ng++)
                acc[fg][ng] = __builtin_amdgcn_mfma_f32_16x16x32_bf16(a[fg], bfr[ng], acc[fg][ng], 0, 0, 0);
    }

    // bias (features vary with jj -> float4 load)
    #pragma unroll
    for (int fg = 0; fg < 2; fg++) {
        float4 bv = *(const float4*)&b[wid * 32 + fg * 16 + 4 * lk];
        #pragma unroll
        for (int ng = 0; ng < 4; ng++) {
            acc[fg][ng][0] += bv.x; acc[fg][ng][1] += bv.y;
            acc[fg][ng][2] += bv.z; acc[fg][ng][3] += bv.w;
        }
    }

    // ---- LayerNorm: per node (col) sum over features ----
    float sv[4], sq[4];
    #pragma unroll
    for (int ng = 0; ng < 4; ng++) {
        float s = 0.f, q = 0.f;
        #pragma unroll
        for (int fg = 0; fg < 2; fg++)
            #pragma unroll
            for (int jj = 0; jj < 4; jj++) {
                float v = acc[fg][ng][jj];
                s += v; q += v * v;
            }
        sv[ng] = s; sq[ng] = q;
    }
    #pragma unroll
    for (int ng = 0; ng < 4; ng++) {
        sv[ng] += __shfl_xor(sv[ng], 16, 64);
        sq[ng] += __shfl_xor(sq[ng], 16, 64);
        sv[ng] += __shfl_xor(sv[ng], 32, 64);
        sq[ng] += __shfl_xor(sq[ng], 32, 64);
    }
    if (lk == 0) {
        #pragma unroll
        for (int ng = 0; ng < 4; ng++) {
            psum[wid][ng * 16 + lr] = sv[ng];
            psq[wid][ng * 16 + lr]  = sq[ng];
        }
    }
    __syncthreads();
    if (t < 64) {
        float s = 0.f, q = 0.f;
        #pragma unroll
        for (int wv = 0; wv < 8; wv++) { s += psum[wv][t]; q += psq[wv][t]; }
        float m = s * (1.f / 256.f);
        float var = q * (1.f / 256.f) - m * m;
        mean_s[t] = m;
        inv_s[t]  = rsqrtf(var + 1e-5f);
    }
    __syncthreads();

    // scale + direct 8B global stores (lane holds 4 consecutive features of one node)
    #pragma unroll
    for (int fg = 0; fg < 2; fg++) {
        int fbase = wid * 32 + fg * 16 + 4 * lk;
        float4 gv  = *(const float4*)&g[fbase];
        float4 btv = *(const float4*)&bt[fbase];
        #pragma unroll
        for (int ng = 0; ng < 4; ng++) {
            int row = ng * 16 + lr;
            size_t node = node0 + row;
            if (node < (size_t)n) {
                float m = mean_s[row];
                float inv = inv_s[row];
                ushort4 h4;
                h4.x = f2bf((acc[fg][ng][0] - m) * inv * gv.x + btv.x);
                h4.y = f2bf((acc[fg][ng][1] - m) * inv * gv.y + btv.y);
                h4.z = f2bf((acc[fg][ng][2] - m) * inv * gv.z + btv.z);
                h4.w = f2bf((acc[fg][ng][3] - m) * inv * gv.w + btv.w);
                *(ushort4*)(xout + node * HDIM + fbase) = h4;
            }
        }
    }
}

// ---------------- plain MFMA GEMM (final projection, bf16 in, fp32 out) ----------------

__global__ __launch_bounds__(256) void k_gemm_final(
    const unsigned short* __restrict__ zin, const unsigned short* __restrict__ Wt,
    const float* __restrict__ b, float* __restrict__ xout, int n) {
    __shared__ __align__(128) unsigned short As[64 * 256];   // 32 KB, 512B/row swizzled

    int t = threadIdx.x;
    int w = t >> 6;
    int l = t & 63;
    size_t node0 = (size_t)blockIdx.x * 64;

    if (node0 + 64 <= (size_t)n) {
        const char* ztile = (const char*)(zin + node0 * HDIM);
        #pragma unroll
        for (int it = 0; it < 8; it++) {
            int ldsbase = w * 8192 + it * 1024;
            int row = (ldsbase >> 9) + (l >> 5);
            int chunk = (l & 31) * 16;
            const char* src = ztile + row * 512 + (chunk ^ ((row & 7) << 4));
            __builtin_amdgcn_global_load_lds((gas_ptr)src,
                                             (las_ptr)((char*)As + ldsbase),
                                             16, 0, 0);
        }
    } else {
        const ushort4* zr = (const ushort4*)(zin + node0 * HDIM);
        #pragma unroll
        for (int i = 0; i < 16; i++) {
            int g4 = i * 256 + t;
            int row = g4 >> 6, c4 = g4 & 63;
            ushort4 v = make_ushort4(0, 0, 0, 0);
            if (node0 + row < (size_t)n) v = zr[g4];
            *(ushort4*)((char*)As + row * 512 + ((c4 << 3) ^ ((row & 7) << 4))) = v;
        }
    }
    __syncthreads();

    int lr = l & 15;
    int lk = l >> 4;

    f32x4 acc[4][4];
    #pragma unroll
    for (int rg = 0; rg < 4; rg++)
        #pragma unroll
        for (int cg = 0; cg < 4; cg++)
            acc[rg][cg] = (f32x4){0.f, 0.f, 0.f, 0.f};

    #pragma unroll
    for (int kt = 0; kt < 8; kt++) {
        int kbyte = kt * 64 + lk * 16;
        short8 a[4], bf[4];
        #pragma unroll
        for (int rg = 0; rg < 4; rg++) {
            int row = rg * 16 + lr;
            a[rg] = *(const short8*)((const char*)As + row * 512 + (kbyte ^ ((row & 7) << 4)));
        }
        #pragma unroll
        for (int cg = 0; cg < 4; cg++) {
            int coln = w * 64 + cg * 16 + lr;
            bf[cg] = *(const short8*)((const char*)Wt + coln * 512 + kbyte);
        }
        #pragma unroll
        for (int rg = 0; rg < 4; rg++)
            #pragma unroll
            for (int cg = 0; cg < 4; cg++)
                acc[rg][cg] = __builtin_amdgcn_mfma_f32_16x16x32_bf16(a[rg], bf[cg], acc[rg][cg], 0, 0, 0);
    }

    float bcol[4];
    #pragma unroll
    for (int cg = 0; cg < 4; cg++) bcol[cg] = b[w * 64 + cg * 16 + lr];
    #pragma unroll
    for (int rg = 0; rg < 4; rg++)
        #pragma unroll
        for (int j = 0; j < 4; j++) {
            int row = rg * 16 + lk * 4 + j;
            size_t node = node0 + row;
            if (node < (size_t)n) {
                #pragma unroll
                for (int cg = 0; cg < 4; cg++)
                    xout[node * HDIM + w * 64 + cg * 16 + lr] = acc[rg][cg][j] + bcol[cg];
            }
        }
}

// ---------------- host ----------------

extern "C" void kernel_launch(void* const* d_in, const int* in_sizes, int n_in,
                              void* d_out, int out_size, void* d_ws, size_t ws_size,
                              hipStream_t stream) {
    const int*   atom = (const int*)d_in[0];
    const int*   src  = (const int*)d_in[1];
    const int*   dst  = (const int*)d_in[2];
    const float* eE   = (const float*)d_in[3];
    const float* eD   = (const float*)d_in[4];
    const float* eV   = (const float*)d_in[5];
    const float* eC   = (const float*)d_in[6];
    const float* eA   = (const float*)d_in[7];
    const float* eH   = (const float*)d_in[8];
    const float* eHy  = (const float*)d_in[9];
    const float* W0   = (const float*)d_in[10];
    const float* b0   = (const float*)d_in[11];
    const float* W1   = (const float*)d_in[12];
    const float* b1   = (const float*)d_in[13];

    const int N = in_sizes[0] / 7;
    const int E = in_sizes[1];
    const int twoE = 2 * E;

    // workspace carve (bf16 ping-pong buffers)
    unsigned short* xb = (unsigned short*)d_ws;          // N x 256 bf16
    unsigned short* z  = xb + (size_t)N * HDIM;          // N x 256 bf16
    int*   rp      = (int*)(z + (size_t)N * HDIM);       // N+1
    int*   cursor  = rp + (N + 1);
    int*   deg     = cursor + N;
    int*   col     = deg + N;                            // 2E
    int*   bsum    = col + twoE;                         // <=1024
    uintptr_t pw = (uintptr_t)(bsum + 1024);
    pw = (pw + 255) & ~(uintptr_t)255;
    unsigned short* Wt  = (unsigned short*)pw;           // 5 x 256 x 256 bf16
    unsigned short* Wt0 = Wt + (size_t)5 * 65536;        // 256 x 96 bf16

    const int nb = (N + 1023) / 1024;

    // CSR build
    k_zero_int<<<(N + 255) / 256, 256, 0, stream>>>(deg, N);
    k_hist<<<(E + 255) / 256, 256, 0, stream>>>(src, dst, E, deg);
    k_scan_partial<<<nb, 256, 0, stream>>>(deg, rp, bsum, N);
    k_scan_bsum<<<1, 256, 0, stream>>>(bsum, nb);
    k_scan_add<<<(N + 255) / 256, 256, 0, stream>>>(rp, cursor, bsum, N, twoE);
    k_fill<<<(E + 255) / 256, 256, 0, stream>>>(src, dst, E, cursor, col);

    // weight prep
    for (int L = 0; L < 4; L++) {
        const float* Wn = (const float*)d_in[14 + 6 * L + 0];
        k_prep_w<<<256, 256, 0, stream>>>(Wn, Wt + (size_t)L * 65536);
    }
    k_prep_w<<<256, 256, 0, stream>>>(W1, Wt + (size_t)4 * 65536);
    k_prep_w0<<<96, 256, 0, stream>>>(W0, Wt0);

    const int nblk64 = (N + 63) / 64;

    // embed + first GEMM -> xb (bf16)
    k_embed0<<<nblk64, 256, 0, stream>>>(atom, eE, eD, eV, eC, eA, eH, eHy,
                                         Wt0, b0, xb, N);

    // 4 fused GINE layers, ping-pong xb <-> z
    unsigned short* cur = xb;
    unsigned short* nxt = z;
    for (int L = 0; L < 4; L++) {
        const float* bn = (const float*)d_in[14 + 6 * L + 1];
        const float* We = (const float*)d_in[14 + 6 * L + 2];
        const float* be = (const float*)d_in[14 + 6 * L + 3];
        const float* gg = (const float*)d_in[14 + 6 * L + 4];
        const float* bt = (const float*)d_in[14 + 6 * L + 5];
        k_gine<<<nblk64, 512, 0, stream>>>(cur, rp, col, We, be,
                                           Wt + (size_t)L * 65536, bn, gg, bt, nxt, N);
        unsigned short* tmp = cur; cur = nxt; nxt = tmp;
    }

    // final projection: cur (== xb after 4 swaps) -> d_out (fp32)
    k_gemm_final<<<nblk64, 256, 0, stream>>>(cur, Wt + (size_t)4 * 65536,
                                             b1, (float*)d_out, N);
}

// Round 12
// 784.491 us; speedup vs baseline: 1.0977x; 1.0977x over previous
//
#include <hip/hip_runtime.h>

#define HDIM 256

typedef __attribute__((ext_vector_type(8))) short short8;
typedef __attribute__((ext_vector_type(4))) float f32x4;

typedef const __attribute__((address_space(1))) unsigned int* gas_ptr;
typedef __attribute__((address_space(3))) unsigned int* las_ptr;

__device__ __forceinline__ unsigned short f2bf(float f) {
    unsigned int u = __float_as_uint(f);
    u += 0x7FFF + ((u >> 16) & 1);   // round-to-nearest-even
    return (unsigned short)(u >> 16);
}
__device__ __forceinline__ float bf2f(unsigned short u) {
    return __uint_as_float(((unsigned int)u) << 16);
}

// ---------------- CSR build ----------------

__global__ void k_zero_int(int* p, int n) {
    int i = blockIdx.x * blockDim.x + threadIdx.x;
    if (i < n) p[i] = 0;
}

__global__ void k_hist(const int* __restrict__ src, const int* __restrict__ dst,
                       int E, int* __restrict__ deg) {
    int e = blockIdx.x * blockDim.x + threadIdx.x;
    if (e >= E) return;
    atomicAdd(&deg[dst[e]], 1);
    atomicAdd(&deg[src[e]], 1);
}

__global__ void k_scan_partial(const int* __restrict__ deg, int* __restrict__ rp,
                               int* __restrict__ bsum, int n) {
    __shared__ int sd[256];
    int t = threadIdx.x;
    int base = blockIdx.x * 1024 + t * 4;
    int v[4]; int tsum = 0;
    #pragma unroll
    for (int k = 0; k < 4; k++) { v[k] = (base + k < n) ? deg[base + k] : 0; tsum += v[k]; }
    sd[t] = tsum; __syncthreads();
    for (int off = 1; off < 256; off <<= 1) {
        int x = (t >= off) ? sd[t - off] : 0;
        __syncthreads();
        sd[t] += x;
        __syncthreads();
    }
    int run = sd[t] - tsum;
    if (t == 255) bsum[blockIdx.x] = sd[255];
    #pragma unroll
    for (int k = 0; k < 4; k++) { if (base + k < n) rp[base + k] = run; run += v[k]; }
}

__global__ void k_scan_bsum(int* __restrict__ bsum, int nb) {
    __shared__ int sd[256];
    int t = threadIdx.x;
    int base = t * 4;
    int v[4]; int tsum = 0;
    #pragma unroll
    for (int k = 0; k < 4; k++) { v[k] = (base + k < nb) ? bsum[base + k] : 0; tsum += v[k]; }
    sd[t] = tsum; __syncthreads();
    for (int off = 1; off < 256; off <<= 1) {
        int x = (t >= off) ? sd[t - off] : 0;
        __syncthreads();
        sd[t] += x;
        __syncthreads();
    }
    int run = sd[t] - tsum;
    #pragma unroll
    for (int k = 0; k < 4; k++) { if (base + k < nb) bsum[base + k] = run; run += v[k]; }
}

__global__ void k_scan_add(int* __restrict__ rp, int* __restrict__ cursor,
                           const int* __restrict__ bsum, int n, int twoE) {
    int i = blockIdx.x * blockDim.x + threadIdx.x;
    if (i < n) {
        int v = rp[i] + bsum[i >> 10];
        rp[i] = v;
        cursor[i] = v;
    }
    if (i == 0) rp[n] = twoE;
}

__global__ void k_fill(const int* __restrict__ src, const int* __restrict__ dst,
                       int E, int* __restrict__ cursor, int* __restrict__ col) {
    int e = blockIdx.x * blockDim.x + threadIdx.x;
    if (e >= E) return;
    int s = src[e], d = dst[e];
    int p = atomicAdd(&cursor[d], 1); col[p] = s;
    int q = atomicAdd(&cursor[s], 1); col[q] = d;
}

// ---------------- weight prep (all 6 matrices in one launch) ----------------
// blocks 0..1279: Wt[L][n][k] = bf16(W_L[k][n]) for L = blockIdx/256
// blocks 1280..1375: Wt0[n][96]: k<88 -> bf16(W0[k][n]) else 0

__global__ void k_prep_all(
    const float* __restrict__ Wn0, const float* __restrict__ Wn1,
    const float* __restrict__ Wn2, const float* __restrict__ Wn3,
    const float* __restrict__ W1, const float* __restrict__ W0,
    unsigned short* __restrict__ Wt, unsigned short* __restrict__ Wt0) {
    int bid = blockIdx.x, nn = threadIdx.x;
    if (bid < 1280) {
        int L = bid >> 8, k = bid & 255;
        const float* W = (L == 0) ? Wn0 : (L == 1) ? Wn1 : (L == 2) ? Wn2
                       : (L == 3) ? Wn3 : W1;
        Wt[(size_t)L * 65536 + nn * 256 + k] = f2bf(W[k * 256 + nn]);
    } else {
        int k = bid - 1280;
        Wt0[nn * 96 + k] = (k < 88) ? f2bf(W0[k * 256 + nn]) : 0;
    }
}

// ---------------- embed + GEMM0 (88 -> 256), MFMA, bf16 out ----------------

__global__ __launch_bounds__(256) void k_embed0(
    const int* __restrict__ atom,
    const float* __restrict__ eE, const float* __restrict__ eD,
    const float* __restrict__ eV, const float* __restrict__ eC,
    const float* __restrict__ eA, const float* __restrict__ eH,
    const float* __restrict__ eHy,
    const unsigned short* __restrict__ Wt0, const float* __restrict__ b0,
    unsigned short* __restrict__ x, int n) {
    __shared__ __align__(128) unsigned short As[64 * 256];  // 32 KB
    int t = threadIdx.x;
    size_t node0 = (size_t)blockIdx.x * 64;

    {
        int row = t >> 2;
        int ks  = (t & 3) * 24;
        size_t node = node0 + row;
        int a0 = 0, a1 = 0, a2 = 0, a3 = 0, a4 = 0, a5 = 0, a6 = 0;
        bool ok = node < (size_t)n;
        if (ok) {
            const int* a = atom + node * 7;
            a0 = a[0]; a1 = a[1]; a2 = a[2]; a3 = a[3]; a4 = a[4]; a5 = a[5]; a6 = a[6];
        }
        #pragma unroll
        for (int kk = 0; kk < 24; kk++) {
            int k = ks + kk;
            float val = 0.f;
            if (ok) {
                if (k < 64)       val = eE[a0 * 64 + k];
                else if (k < 68)  val = eD[a1 * 4 + (k - 64)];
                else if (k < 72)  val = eV[(a2 + 1) * 4 + (k - 68)];
                else if (k < 76)  val = eC[a3 * 4 + (k - 72)];
                else if (k < 80)  val = eA[a4 * 4 + (k - 76)];
                else if (k < 84)  val = eH[a5 * 4 + (k - 80)];
                else if (k < 88)  val = eHy[a6 * 4 + (k - 84)];
            }
            int boff = (k * 2) ^ ((row & 7) << 4);
            *(unsigned short*)((char*)As + row * 256 + boff) = f2bf(val);
        }
    }
    __syncthreads();

    int w  = t >> 6;
    int l  = t & 63;
    int lr = l & 15;
    int lk = l >> 4;

    f32x4 acc[4][4];
    #pragma unroll
    for (int rg = 0; rg < 4; rg++)
        #pragma unroll
        for (int cg = 0; cg < 4; cg++)
            acc[rg][cg] = (f32x4){0.f, 0.f, 0.f, 0.f};

    #pragma unroll
    for (int kt = 0; kt < 3; kt++) {
        int kbyte = kt * 64 + lk * 16;
        short8 a[4], bf[4];
        #pragma unroll
        for (int rg = 0; rg < 4; rg++) {
            int row = rg * 16 + lr;
            a[rg] = *(const short8*)((const char*)As + row * 256 + (kbyte ^ ((row & 7) << 4)));
        }
        #pragma unroll
        for (int cg = 0; cg < 4; cg++) {
            int coln = w * 64 + cg * 16 + lr;
            bf[cg] = *(const short8*)((const char*)Wt0 + coln * 192 + kbyte);
        }
        #pragma unroll
        for (int rg = 0; rg < 4; rg++)
            #pragma unroll
            for (int cg = 0; cg < 4; cg++)
                acc[rg][cg] = __builtin_amdgcn_mfma_f32_16x16x32_bf16(a[rg], bf[cg], acc[rg][cg], 0, 0, 0);
    }

    float bcol[4];
    #pragma unroll
    for (int cg = 0; cg < 4; cg++) bcol[cg] = b0[w * 64 + cg * 16 + lr];

    __syncthreads();   // As reads done; reuse for bf16 repack (512B/row swizzled)
    #pragma unroll
    for (int rg = 0; rg < 4; rg++)
        #pragma unroll
        for (int j = 0; j < 4; j++) {
            int row = rg * 16 + lk * 4 + j;
            #pragma unroll
            for (int cg = 0; cg < 4; cg++) {
                int colI = w * 64 + cg * 16 + lr;
                int byte = row * 512 + ((((colI >> 2) << 3) ^ ((row & 7) << 4)) + (colI & 3) * 2);
                *(unsigned short*)((char*)As + byte) = f2bf(acc[rg][cg][j] + bcol[cg]);
            }
        }
    __syncthreads();
    ushort4* xo = (ushort4*)(x + node0 * HDIM);
    #pragma unroll
    for (int i = 0; i < 16; i++) {
        int g4 = i * 256 + t;
        int row = g4 >> 6, c4 = g4 & 63;
        if (node0 + row < (size_t)n)
            xo[g4] = *(ushort4*)((char*)As + row * 512 + ((c4 << 3) ^ ((row & 7) << 4)));
    }
}

// ---------------- fused GINE layer: gather -> LDS -> MFMA -> LN -> bf16 out ----------------
// (round-9 version: static half-wave schedule, LDS-repack epilogue — best measured)

__global__ __launch_bounds__(512) void k_gine(
    const unsigned short* __restrict__ x, const int* __restrict__ rp,
    const int* __restrict__ col, const float* __restrict__ We,
    const float* __restrict__ be, const unsigned short* __restrict__ Wt,
    const float* __restrict__ b, const float* __restrict__ g,
    const float* __restrict__ bt, unsigned short* __restrict__ xout, int n) {
    __shared__ __align__(128) unsigned short As[64 * 256];   // 32 KB, 512B/row swizzled
    __shared__ float psum[8][64], psq[8][64];
    __shared__ float mean_s[64], inv_s[64];

    int t = threadIdx.x;
    int wid = t >> 6;       // 0..7
    int l = t & 63;
    int h = l >> 5;
    int j = l & 31;
    size_t node0 = (size_t)blockIdx.x * 64;

    // ---- phase 1: gather + relu + sum, write rows to LDS ----
    {
        int hh = wid * 2 + h;                  // 0..15, each does 4 rows
        const short8* x8 = (const short8*)x;   // 32 chunks of 16B per row
        float c[8];
        {
            float4 w0 = ((const float4*)We)[2 * j], w1 = ((const float4*)We)[2 * j + 1];
            float4 e0 = ((const float4*)be)[2 * j], e1 = ((const float4*)be)[2 * j + 1];
            c[0] = w0.x + e0.x; c[1] = w0.y + e0.y; c[2] = w0.z + e0.z; c[3] = w0.w + e0.w;
            c[4] = w1.x + e1.x; c[5] = w1.y + e1.y; c[6] = w1.z + e1.z; c[7] = w1.w + e1.w;
        }
        for (int q = 0; q < 4; q++) {
            int row = hh * 4 + q;
            size_t node = node0 + row;
            bool ok = node < (size_t)n;
            int nd = ok ? (int)node : 0;
            int p0 = rp[nd], p1 = rp[nd + 1];
            int deg = ok ? (p1 - p0) : 0;

            float acc[8];
            short8 s = x8[(size_t)nd * 32 + j];
            #pragma unroll
            for (int k = 0; k < 8; k++) acc[k] = ok ? bf2f((unsigned short)s[k]) : 0.f;

            for (int bb = 0; bb < deg; bb += 32) {
                int m = deg - bb; if (m > 32) m = 32;
                int idx = (j < m) ? col[p0 + bb + j] : 0;
                int e = 0;
                for (; e + 2 <= m; e += 2) {
                    int s0 = __shfl(idx, (h << 5) + e, 64);
                    int s1 = __shfl(idx, (h << 5) + e + 1, 64);
                    short8 u0 = x8[(size_t)s0 * 32 + j];
                    short8 u1 = x8[(size_t)s1 * 32 + j];
                    #pragma unroll
                    for (int k = 0; k < 8; k++) acc[k] += fmaxf(bf2f((unsigned short)u0[k]) + c[k], 0.f);
                    #pragma unroll
                    for (int k = 0; k < 8; k++) acc[k] += fmaxf(bf2f((unsigned short)u1[k]) + c[k], 0.f);
                }
                if (e < m) {
                    int s0 = __shfl(idx, (h << 5) + e, 64);
                    short8 u0 = x8[(size_t)s0 * 32 + j];
                    #pragma unroll
                    for (int k = 0; k < 8; k++) acc[k] += fmaxf(bf2f((unsigned short)u0[k]) + c[k], 0.f);
                }
            }

            short8 o;
            #pragma unroll
            for (int k = 0; k < 8; k++) o[k] = (short)f2bf(acc[k]);
            *(short8*)((char*)As + row * 512 + ((j ^ (row & 7)) << 4)) = o;
        }
    }
    __syncthreads();

    // ---- phase 2: MFMA (A = Wt features, B = node rows) ----
    int lr = l & 15;
    int lk = l >> 4;

    f32x4 acc[2][4];        // [fg][ng]
    #pragma unroll
    for (int fg = 0; fg < 2; fg++)
        #pragma unroll
        for (int ng = 0; ng < 4; ng++)
            acc[fg][ng] = (f32x4){0.f, 0.f, 0.f, 0.f};

    #pragma unroll
    for (int kt = 0; kt < 8; kt++) {
        int kbyte = kt * 64 + lk * 16;
        short8 a[2], bfr[4];
        #pragma unroll
        for (int fg = 0; fg < 2; fg++) {
            int feat = wid * 32 + fg * 16 + lr;
            a[fg] = *(const short8*)((const char*)Wt + feat * 512 + kbyte);
        }
        #pragma unroll
        for (int ng = 0; ng < 4; ng++) {
            int row = ng * 16 + lr;
            bfr[ng] = *(const short8*)((const char*)As + row * 512 + (kbyte ^ ((row & 7) << 4)));
        }
        #pragma unroll
        for (int fg = 0; fg < 2; fg++)
            #pragma unroll
            for (int ng = 0; ng < 4; ng++)
                acc[fg][ng] = __builtin_amdgcn_mfma_f32_16x16x32_bf16(a[fg], bfr[ng], acc[fg][ng], 0, 0, 0);
    }

    // bias (features vary with jj -> float4 load)
    #pragma unroll
    for (int fg = 0; fg < 2; fg++) {
        float4 bv = *(const float4*)&b[wid * 32 + fg * 16 + 4 * lk];
        #pragma unroll
        for (int ng = 0; ng < 4; ng++) {
            acc[fg][ng][0] += bv.x; acc[fg][ng][1] += bv.y;
            acc[fg][ng][2] += bv.z; acc[fg][ng][3] += bv.w;
        }
    }

    // ---- LayerNorm: per node (col) sum over features ----
    float sv[4], sq[4];
    #pragma unroll
    for (int ng = 0; ng < 4; ng++) {
        float s = 0.f, q = 0.f;
        #pragma unroll
        for (int fg = 0; fg < 2; fg++)
            #pragma unroll
            for (int jj = 0; jj < 4; jj++) {
                float v = acc[fg][ng][jj];
                s += v; q += v * v;
            }
        sv[ng] = s; sq[ng] = q;
    }
    #pragma unroll
    for (int ng = 0; ng < 4; ng++) {
        sv[ng] += __shfl_xor(sv[ng], 16, 64);
        sq[ng] += __shfl_xor(sq[ng], 16, 64);
        sv[ng] += __shfl_xor(sv[ng], 32, 64);
        sq[ng] += __shfl_xor(sq[ng], 32, 64);
    }
    if (lk == 0) {
        #pragma unroll
        for (int ng = 0; ng < 4; ng++) {
            psum[wid][ng * 16 + lr] = sv[ng];
            psq[wid][ng * 16 + lr]  = sq[ng];
        }
    }
    __syncthreads();
    if (t < 64) {
        float s = 0.f, q = 0.f;
        #pragma unroll
        for (int wv = 0; wv < 8; wv++) { s += psum[wv][t]; q += psq[wv][t]; }
        float m = s * (1.f / 256.f);
        float var = q * (1.f / 256.f) - m * m;
        mean_s[t] = m;
        inv_s[t]  = rsqrtf(var + 1e-5f);
    }
    __syncthreads();

    // scale + pack bf16 -> 8B LDS writes (swizzled), then coalesced out
    #pragma unroll
    for (int fg = 0; fg < 2; fg++) {
        int fbase = wid * 32 + fg * 16 + 4 * lk;
        float4 gv  = *(const float4*)&g[fbase];
        float4 btv = *(const float4*)&bt[fbase];
        #pragma unroll
        for (int ng = 0; ng < 4; ng++) {
            int row = ng * 16 + lr;
            float m = mean_s[row];
            float inv = inv_s[row];
            ushort4 h4;
            h4.x = f2bf((acc[fg][ng][0] - m) * inv * gv.x + btv.x);
            h4.y = f2bf((acc[fg][ng][1] - m) * inv * gv.y + btv.y);
            h4.z = f2bf((acc[fg][ng][2] - m) * inv * gv.z + btv.z);
            h4.w = f2bf((acc[fg][ng][3] - m) * inv * gv.w + btv.w);
            int byte = row * 512 + ((fbase * 2) ^ ((row & 7) << 4));
            *(ushort4*)((char*)As + byte) = h4;
        }
    }
    __syncthreads();
    #pragma unroll
    for (int i = 0; i < 4; i++) {
        int g16 = i * 512 + t;          // 16B-chunk index, 2048 total
        int row = g16 >> 5, ch = g16 & 31;
        if (node0 + row < (size_t)n) {
            short8 v = *(const short8*)((const char*)As + row * 512 + ((ch ^ (row & 7)) << 4));
            ((short8*)xout)[(node0 + row) * 32 + ch] = v;
        }
    }
}

// ---------------- plain MFMA GEMM (final projection, bf16 in, fp32 out) ----------------

__global__ __launch_bounds__(256) void k_gemm_final(
    const unsigned short* __restrict__ zin, const unsigned short* __restrict__ Wt,
    const float* __restrict__ b, float* __restrict__ xout, int n) {
    __shared__ __align__(128) unsigned short As[64 * 256];   // 32 KB, 512B/row swizzled

    int t = threadIdx.x;
    int w = t >> 6;
    int l = t & 63;
    size_t node0 = (size_t)blockIdx.x * 64;

    if (node0 + 64 <= (size_t)n) {
        const char* ztile = (const char*)(zin + node0 * HDIM);
        #pragma unroll
        for (int it = 0; it < 8; it++) {
            int ldsbase = w * 8192 + it * 1024;
            int row = (ldsbase >> 9) + (l >> 5);
            int chunk = (l & 31) * 16;
            const char* src = ztile + row * 512 + (chunk ^ ((row & 7) << 4));
            __builtin_amdgcn_global_load_lds((gas_ptr)src,
                                             (las_ptr)((char*)As + ldsbase),
                                             16, 0, 0);
        }
    } else {
        const ushort4* zr = (const ushort4*)(zin + node0 * HDIM);
        #pragma unroll
        for (int i = 0; i < 16; i++) {
            int g4 = i * 256 + t;
            int row = g4 >> 6, c4 = g4 & 63;
            ushort4 v = make_ushort4(0, 0, 0, 0);
            if (node0 + row < (size_t)n) v = zr[g4];
            *(ushort4*)((char*)As + row * 512 + ((c4 << 3) ^ ((row & 7) << 4))) = v;
        }
    }
    __syncthreads();

    int lr = l & 15;
    int lk = l >> 4;

    f32x4 acc[4][4];
    #pragma unroll
    for (int rg = 0; rg < 4; rg++)
        #pragma unroll
        for (int cg = 0; cg < 4; cg++)
            acc[rg][cg] = (f32x4){0.f, 0.f, 0.f, 0.f};

    #pragma unroll
    for (int kt = 0; kt < 8; kt++) {
        int kbyte = kt * 64 + lk * 16;
        short8 a[4], bf[4];
        #pragma unroll
        for (int rg = 0; rg < 4; rg++) {
            int row = rg * 16 + lr;
            a[rg] = *(const short8*)((const char*)As + row * 512 + (kbyte ^ ((row & 7) << 4)));
        }
        #pragma unroll
        for (int cg = 0; cg < 4; cg++) {
            int coln = w * 64 + cg * 16 + lr;
            bf[cg] = *(const short8*)((const char*)Wt + coln * 512 + kbyte);
        }
        #pragma unroll
        for (int rg = 0; rg < 4; rg++)
            #pragma unroll
            for (int cg = 0; cg < 4; cg++)
                acc[rg][cg] = __builtin_amdgcn_mfma_f32_16x16x32_bf16(a[rg], bf[cg], acc[rg][cg], 0, 0, 0);
    }

    float bcol[4];
    #pragma unroll
    for (int cg = 0; cg < 4; cg++) bcol[cg] = b[w * 64 + cg * 16 + lr];
    #pragma unroll
    for (int rg = 0; rg < 4; rg++)
        #pragma unroll
        for (int j = 0; j < 4; j++) {
            int row = rg * 16 + lk * 4 + j;
            size_t node = node0 + row;
            if (node < (size_t)n) {
                #pragma unroll
                for (int cg = 0; cg < 4; cg++)
                    xout[node * HDIM + w * 64 + cg * 16 + lr] = acc[rg][cg][j] + bcol[cg];
            }
        }
}

// ---------------- host ----------------

extern "C" void kernel_launch(void* const* d_in, const int* in_sizes, int n_in,
                              void* d_out, int out_size, void* d_ws, size_t ws_size,
                              hipStream_t stream) {
    const int*   atom = (const int*)d_in[0];
    const int*   src  = (const int*)d_in[1];
    const int*   dst  = (const int*)d_in[2];
    const float* eE   = (const float*)d_in[3];
    const float* eD   = (const float*)d_in[4];
    const float* eV   = (const float*)d_in[5];
    const float* eC   = (const float*)d_in[6];
    const float* eA   = (const float*)d_in[7];
    const float* eH   = (const float*)d_in[8];
    const float* eHy  = (const float*)d_in[9];
    const float* W0   = (const float*)d_in[10];
    const float* b0   = (const float*)d_in[11];
    const float* W1   = (const float*)d_in[12];
    const float* b1   = (const float*)d_in[13];

    const int N = in_sizes[0] / 7;
    const int E = in_sizes[1];
    const int twoE = 2 * E;

    // workspace carve (bf16 ping-pong buffers)
    unsigned short* xb = (unsigned short*)d_ws;          // N x 256 bf16
    unsigned short* z  = xb + (size_t)N * HDIM;          // N x 256 bf16
    int*   rp      = (int*)(z + (size_t)N * HDIM);       // N+1
    int*   cursor  = rp + (N + 1);
    int*   deg     = cursor + N;
    int*   col     = deg + N;                            // 2E
    int*   bsum    = col + twoE;                         // <=1024
    uintptr_t pw = (uintptr_t)(bsum + 1024);
    pw = (pw + 255) & ~(uintptr_t)255;
    unsigned short* Wt  = (unsigned short*)pw;           // 5 x 256 x 256 bf16
    unsigned short* Wt0 = Wt + (size_t)5 * 65536;        // 256 x 96 bf16

    const int nb = (N + 1023) / 1024;

    // CSR build
    k_zero_int<<<(N + 255) / 256, 256, 0, stream>>>(deg, N);
    k_hist<<<(E + 255) / 256, 256, 0, stream>>>(src, dst, E, deg);
    k_scan_partial<<<nb, 256, 0, stream>>>(deg, rp, bsum, N);
    k_scan_bsum<<<1, 256, 0, stream>>>(bsum, nb);
    k_scan_add<<<(N + 255) / 256, 256, 0, stream>>>(rp, cursor, bsum, N, twoE);
    k_fill<<<(E + 255) / 256, 256, 0, stream>>>(src, dst, E, cursor, col);

    // weight prep (single launch for all 6 matrices)
    {
        const float* Wn0 = (const float*)d_in[14];
        const float* Wn1 = (const float*)d_in[20];
        const float* Wn2 = (const float*)d_in[26];
        const float* Wn3 = (const float*)d_in[32];
        k_prep_all<<<1376, 256, 0, stream>>>(Wn0, Wn1, Wn2, Wn3, W1, W0, Wt, Wt0);
    }

    const int nblk64 = (N + 63) / 64;

    // embed + first GEMM -> xb (bf16)
    k_embed0<<<nblk64, 256, 0, stream>>>(atom, eE, eD, eV, eC, eA, eH, eHy,
                                         Wt0, b0, xb, N);

    // 4 fused GINE layers, ping-pong xb <-> z
    unsigned short* cur = xb;
    unsigned short* nxt = z;
    for (int L = 0; L < 4; L++) {
        const float* bn = (const float*)d_in[14 + 6 * L + 1];
        const float* We = (const float*)d_in[14 + 6 * L + 2];
        const float* be = (const float*)d_in[14 + 6 * L + 3];
        const float* gg = (const float*)d_in[14 + 6 * L + 4];
        const float* bt = (const float*)d_in[14 + 6 * L + 5];
        k_gine<<<nblk64, 512, 0, stream>>>(cur, rp, col, We, be,
                                           Wt + (size_t)L * 65536, bn, gg, bt, nxt, N);
        unsigned short* tmp = cur; cur = nxt; nxt = tmp;
    }

    // final projection: cur (== xb after 4 swaps) -> d_out (fp32)
    k_gemm_final<<<nblk64, 256, 0, stream>>>(cur, Wt + (size_t)4 * 65536,
                                             b1, (float*)d_out, N);
}